// Round 11
// baseline (45.194 us; speedup 1.0000x reference)
//
#include <hip/hip_runtime.h>
#include <hip/hip_bf16.h>

// NT-Xent loss, fused flash-LSE over sim = z z^T / T, bf16 32x32x16 MFMA.
// z pre-packed FRAGMENT-MAJOR zf (convert kernel):
//   zf[((tile*8 + ks)*64 + l) * 8 .. +8] =
//       bf16(z[tile*32 + (l&31)][(l>>5)*8 + ks*16 .. +8] * PRESCALE)
// ROUND 11: additive pipe model from R6/R9 data: per tile-unit per CU the
// terms are L1-port 128cyc + MFMA 65 + TRANS 68 + VALU 40. Each prior round
// fixed ONE term while regressing occupancy. This round combines all three:
//  - LDS-staged A shared by 4 waves/block (L1 term /4)      [from R9]
//  - wave-uniform exp2 skip (TRANS term ~0)                  [from R10]
//  - 32 rows/wave, ~105 VGPR < 128 cliff -> 4 waves/SIMD     [from R6]
// One barrier per tile, double-buffered, 2048 blocks (8/CU).

#define N_TOT 8192
#define B_HALF 4096
#define DIM 128
#define SPLITS 32
#define COLS_PER_SPLIT 256
#define NT 8                               // col-tiles of 32 per block
#define PRESCALE 4.5398159686f             // sqrt(log2(e)/0.07)
#define LN2F 0.6931471805599453f
#define SKIP_MARGIN 30.0f                  // skip tile if tmax <= m - 30 (log2)

typedef __attribute__((ext_vector_type(8))) short bf16x8;
typedef __attribute__((ext_vector_type(16))) float f32x16;

__device__ __forceinline__ unsigned short f2bf_rne(float f) {
    unsigned int u = __float_as_uint(f);
    u += 0x7FFFu + ((u >> 16) & 1u);
    return (unsigned short)(u >> 16);
}

__device__ __forceinline__ void gload16(const void* g, void* l) {
    __builtin_amdgcn_global_load_lds(
        (const __attribute__((address_space(1))) unsigned int*)g,
        (__attribute__((address_space(3))) unsigned int*)l, 16, 0, 0);
}

// ---- kernel 1: convert f32 z_i,z_j -> pre-scaled bf16 fragment-major zf ----
__global__ void convert_kernel(const float* __restrict__ zi,
                               const float* __restrict__ zj,
                               unsigned short* __restrict__ zf) {
    int t = blockIdx.x * 256 + threadIdx.x;   // slot 0..131071
    int l = t & 63;                           // lane slot
    int ks = (t >> 6) & 7;                    // k-step
    int tile = t >> 9;                        // 32-row tile
    int r = tile * 32 + (l & 31);
    int c = (l >> 5) * 8 + ks * 16;
    long si = (long)r * DIM + c;
    const float* src = (si < (long)B_HALF * DIM) ? (zi + si) : (zj + (si - (long)B_HALF * DIM));
    float4 v0 = *(const float4*)src;
    float4 v1 = *(const float4*)(src + 4);
    bf16x8 o;
    o[0] = (short)f2bf_rne(v0.x * PRESCALE);
    o[1] = (short)f2bf_rne(v0.y * PRESCALE);
    o[2] = (short)f2bf_rne(v0.z * PRESCALE);
    o[3] = (short)f2bf_rne(v0.w * PRESCALE);
    o[4] = (short)f2bf_rne(v1.x * PRESCALE);
    o[5] = (short)f2bf_rne(v1.y * PRESCALE);
    o[6] = (short)f2bf_rne(v1.z * PRESCALE);
    o[7] = (short)f2bf_rne(v1.w * PRESCALE);
    *(bf16x8*)(zf + (size_t)t * 8) = o;
}

// consume one 32x32 result tile (acc) for rows [rbase, rbase+32) at
// stream-col base cb into (mv, sv, pv). Deferred-max LSE; wave-uniform skip.
#define CONSUME(accv, mv, sv, pv, rbase, cbv)                                  \
    do {                                                                       \
        const int cb_ = (cbv);                                                 \
        const int rb_ = (rbase);                                               \
        const bool check_ = (cb_ == rb_ || cb_ == (rb_ ^ B_HALF));             \
        if (check_) {                                                          \
            const int j_ = rb_ + l5;                                           \
            _Pragma("unroll")                                                  \
            for (int q = 0; q < 16; ++q) {                                     \
                int iq = cb_ + (q & 3) + 8 * (q >> 2) + 4 * hb;                \
                if (iq == j_) accv[q] = -INFINITY;                             \
                else if (iq == (j_ ^ B_HALF)) pv = accv[q];                    \
            }                                                                  \
        }                                                                      \
        float x0 = fmaxf(fmaxf(accv[0], accv[1]), accv[2]);                    \
        float x1 = fmaxf(fmaxf(accv[3], accv[4]), accv[5]);                    \
        float x2 = fmaxf(fmaxf(accv[6], accv[7]), accv[8]);                    \
        float x3 = fmaxf(fmaxf(accv[9], accv[10]), accv[11]);                  \
        float x4 = fmaxf(fmaxf(accv[12], accv[13]), accv[14]);                 \
        float y0 = fmaxf(fmaxf(x0, x1), x2);                                   \
        float y1 = fmaxf(fmaxf(x3, x4), accv[15]);                             \
        float tmax = fmaxf(y0, y1);                                            \
        if (check_ || !__all(tmax <= mv - SKIP_MARGIN)) {                      \
            float mn = fmaxf(tmax, mv);                                        \
            float rr = __builtin_amdgcn_exp2f(mv - mn); /* exp2(0)=1 */        \
            float e0 = __builtin_amdgcn_exp2f(accv[0] - mn);                   \
            float e1 = __builtin_amdgcn_exp2f(accv[1] - mn);                   \
            float e2 = __builtin_amdgcn_exp2f(accv[2] - mn);                   \
            float e3 = __builtin_amdgcn_exp2f(accv[3] - mn);                   \
            float e4 = __builtin_amdgcn_exp2f(accv[4] - mn);                   \
            float e5 = __builtin_amdgcn_exp2f(accv[5] - mn);                   \
            float e6 = __builtin_amdgcn_exp2f(accv[6] - mn);                   \
            float e7 = __builtin_amdgcn_exp2f(accv[7] - mn);                   \
            float e8 = __builtin_amdgcn_exp2f(accv[8] - mn);                   \
            float e9 = __builtin_amdgcn_exp2f(accv[9] - mn);                   \
            float ea = __builtin_amdgcn_exp2f(accv[10] - mn);                  \
            float eb = __builtin_amdgcn_exp2f(accv[11] - mn);                  \
            float ec = __builtin_amdgcn_exp2f(accv[12] - mn);                  \
            float ed = __builtin_amdgcn_exp2f(accv[13] - mn);                  \
            float ee = __builtin_amdgcn_exp2f(accv[14] - mn);                  \
            float ef = __builtin_amdgcn_exp2f(accv[15] - mn);                  \
            float t0 = (e0 + e1) + (e2 + e3);                                  \
            float t1 = (e4 + e5) + (e6 + e7);                                  \
            float t2 = (e8 + e9) + (ea + eb);                                  \
            float t3 = (ec + ed) + (ee + ef);                                  \
            sv = sv * rr + ((t0 + t1) + (t2 + t3));                            \
            mv = mn;                                                           \
        }                                                                      \
    } while (0)

#define ZERO16(accv)                                                           \
    do { _Pragma("unroll") for (int q = 0; q < 16; ++q) accv[q] = 0.f; } while (0)

// wave w stages fragments 2w, 2w+1 of col-tile (tIdx0 + t) into lds[b]
#define STAGE(t, b)                                                            \
    do {                                                                       \
        const unsigned short* s_ =                                             \
            zf + ((size_t)(tIdx0 + (t)) * 8 + 2 * w) * 512 + l * 8;            \
        gload16(s_, &lds[b][(2 * w) * 64]);                                    \
        gload16(s_ + 512, &lds[b][(2 * w + 1) * 64]);                          \
    } while (0)

// ---- kernel 2: main fused GEMM + online LSE (LDS-staged shared A, reg B) ----
// grid: 64 row-blocks (128 rows: 4 waves x 32) x 32 col-splits (256 cols)
// = 2048 blocks x 256 threads (8 blocks/CU). Wave w owns rows rb*128+w*32;
// the block's 4 waves SHARE each staged 8KB col-tile (different rows).
__global__ __launch_bounds__(256, 4) void ntxent_main(
        const unsigned short* __restrict__ zf,
        float* __restrict__ Wm, float* __restrict__ Ws, float* __restrict__ Wp) {
    __shared__ bf16x8 lds[2][512];  // 2 x 8KB col-tile buffers

    const int bid = blockIdx.x;
    const int rb = bid / SPLITS;
    const int sp = bid % SPLITS;
    const int tid = threadIdx.x;
    const int w = tid >> 6;
    const int l = tid & 63;
    const int l5 = l & 31;
    const int hb = l >> 5;

    const int rowbase = rb * 128 + w * 32;
    const int cb0 = sp * COLS_PER_SPLIT;
    const int tIdx0 = cb0 >> 5;

    // B fragments: one 32-row tile-set (8 x 1KB coalesced loads)
    const unsigned short* bp = zf + (size_t)(rowbase >> 5) * 4096 + l * 8;
    bf16x8 b0 = *(const bf16x8*)(bp + 0 * 512);
    bf16x8 b1 = *(const bf16x8*)(bp + 1 * 512);
    bf16x8 b2 = *(const bf16x8*)(bp + 2 * 512);
    bf16x8 b3 = *(const bf16x8*)(bp + 3 * 512);
    bf16x8 b4 = *(const bf16x8*)(bp + 4 * 512);
    bf16x8 b5 = *(const bf16x8*)(bp + 5 * 512);
    bf16x8 b6 = *(const bf16x8*)(bp + 6 * 512);
    bf16x8 b7 = *(const bf16x8*)(bp + 7 * 512);

    float m0 = -INFINITY, s0 = 0.f, p0 = -INFINITY;
    f32x16 acc;

    STAGE(0, 0);   // prologue

#pragma unroll 2
    for (int t = 0; t < NT; ++t) {
        // own stage(t) loads are the newest VMEM -> vmcnt(0) completes them
        asm volatile("s_waitcnt vmcnt(0)" ::: "memory");
        __builtin_amdgcn_s_barrier();   // stage(t) done; buf[(t+1)&1] free
        __builtin_amdgcn_sched_barrier(0);
        if (t + 1 < NT) STAGE(t + 1, (t + 1) & 1);

        const bf16x8* Lb = lds[t & 1];
        bf16x8 f0 = Lb[0 * 64 + l];
        bf16x8 f1 = Lb[1 * 64 + l];
        bf16x8 f2 = Lb[2 * 64 + l];
        bf16x8 f3 = Lb[3 * 64 + l];
        bf16x8 f4 = Lb[4 * 64 + l];
        bf16x8 f5 = Lb[5 * 64 + l];
        bf16x8 f6 = Lb[6 * 64 + l];
        bf16x8 f7 = Lb[7 * 64 + l];

        ZERO16(acc);
        acc = __builtin_amdgcn_mfma_f32_32x32x16_bf16(f0, b0, acc, 0, 0, 0);
        acc = __builtin_amdgcn_mfma_f32_32x32x16_bf16(f1, b1, acc, 0, 0, 0);
        acc = __builtin_amdgcn_mfma_f32_32x32x16_bf16(f2, b2, acc, 0, 0, 0);
        acc = __builtin_amdgcn_mfma_f32_32x32x16_bf16(f3, b3, acc, 0, 0, 0);
        acc = __builtin_amdgcn_mfma_f32_32x32x16_bf16(f4, b4, acc, 0, 0, 0);
        acc = __builtin_amdgcn_mfma_f32_32x32x16_bf16(f5, b5, acc, 0, 0, 0);
        acc = __builtin_amdgcn_mfma_f32_32x32x16_bf16(f6, b6, acc, 0, 0, 0);
        acc = __builtin_amdgcn_mfma_f32_32x32x16_bf16(f7, b7, acc, 0, 0, 0);

        CONSUME(acc, m0, s0, p0, rowbase, cb0 + t * 32);
    }

    // lanes l and l^32 hold the same row over disjoint col subsets: merge
    {
        float m2 = __shfl_xor(m0, 32);
        float s2 = __shfl_xor(s0, 32);
        float q2 = __shfl_xor(p0, 32);
        float M = fmaxf(m0, m2);
        s0 = s0 * __builtin_amdgcn_exp2f(m0 - M) + s2 * __builtin_amdgcn_exp2f(m2 - M);
        p0 = fmaxf(p0, q2);
        if (l < 32) {
            int r = rowbase + l;
            Wm[sp * N_TOT + r] = M;
            Ws[sp * N_TOT + r] = s0;
            Wp[sp * N_TOT + r] = p0;
        }
    }
}

// ---- kernel 3: merge splits, compute loss, reduce ----
__global__ void merge_kernel(const float* __restrict__ Wm,
                             const float* __restrict__ Ws,
                             const float* __restrict__ Wp,
                             float* __restrict__ out) {
    int r = blockIdx.x * 256 + threadIdx.x; // 0..8191
    float m = -INFINITY, s = 0.f, p = -INFINITY;
#pragma unroll
    for (int sb = 0; sb < SPLITS; ++sb) {
        float m2 = Wm[sb * N_TOT + r];
        float s2 = Ws[sb * N_TOT + r];
        float p2 = Wp[sb * N_TOT + r];
        float M = fmaxf(m, m2);
        s = s * __builtin_amdgcn_exp2f(m - M) + s2 * __builtin_amdgcn_exp2f(m2 - M);
        m = M;
        p = fmaxf(p, p2);
    }
    // aug row = [pos, neg-row]: add exp(pos) once more
    s += __builtin_amdgcn_exp2f(p - m);
    float loss = ((m + __builtin_amdgcn_logf(s)) - p) * LN2F;

#pragma unroll
    for (int off = 32; off >= 1; off >>= 1)
        loss += __shfl_down(loss, off);
    __shared__ float wsum[4];
    if ((threadIdx.x & 63) == 0) wsum[threadIdx.x >> 6] = loss;
    __syncthreads();
    if (threadIdx.x == 0) {
        float t = wsum[0] + wsum[1] + wsum[2] + wsum[3];
        atomicAdd(out, t * (1.0f / (float)N_TOT));
    }
}

extern "C" void kernel_launch(void* const* d_in, const int* in_sizes, int n_in,
                              void* d_out, int out_size, void* d_ws, size_t ws_size,
                              hipStream_t stream) {
    const float* zi = (const float*)d_in[0];
    const float* zj = (const float*)d_in[1];
    float* out = (float*)d_out;

    unsigned short* zf = (unsigned short*)d_ws;                // 2 MB
    float* Wm = (float*)((char*)d_ws + (size_t)N_TOT * DIM * 2);
    float* Ws = Wm + SPLITS * N_TOT;
    float* Wp = Ws + SPLITS * N_TOT;

    hipMemsetAsync(d_out, 0, sizeof(float), stream);
    convert_kernel<<<(N_TOT * DIM / 8) / 256, 256, 0, stream>>>(zi, zj, zf);
    ntxent_main<<<64 * SPLITS, 256, 0, stream>>>(zf, Wm, Ws, Wp);
    merge_kernel<<<N_TOT / 256, 256, 0, stream>>>(Wm, Ws, Wp, out);
}

// Round 12
// 44.600 us; speedup vs baseline: 1.0133x; 1.0133x over previous
//
#include <hip/hip_runtime.h>
#include <hip/hip_bf16.h>

// NT-Xent loss, fused flash-LSE over sim = z z^T / T, bf16 32x32x16 MFMA.
// z pre-packed FRAGMENT-MAJOR zf (convert kernel):
//   zf[((tile*8 + ks)*64 + l) * 8 .. +8] =
//       bf16(z[tile*32 + (l&31)][(l>>5)*8 + ks*16 .. +8] * PRESCALE)
// ROUND 12: R7-R11 proved time is invariant to VMEM bytes, LDS, occupancy
// 2-vs-4, skip, fences -> latency-bound on the per-wave serial chain
// (ds_read ~120 + 8 DEPENDENT MFMAs ~256 + consume ~100 per tile, no pipe
// >35% busy). Fix the DEPENDENCE STRUCTURE: software-pipeline CONSUME(t-1)
// into tile t's ds_read/MFMA latency shadow. Issue order per tile:
//   stage(t+1) -> ds_read(t) -> CONSUME(t-1) [indep VALU] -> MFMA8(t).
// Two named accumulators alternate (static, fully unrolled steps).
// Keeps: LDS-staged shared A (R9), exp2 skip (R10), 4 waves/SIMD (R11).

#define N_TOT 8192
#define B_HALF 4096
#define DIM 128
#define SPLITS 32
#define COLS_PER_SPLIT 256
#define NT 8                               // col-tiles of 32 per block
#define PRESCALE 4.5398159686f             // sqrt(log2(e)/0.07)
#define LN2F 0.6931471805599453f
#define SKIP_MARGIN 30.0f                  // skip tile if tmax <= m - 30 (log2)

typedef __attribute__((ext_vector_type(8))) short bf16x8;
typedef __attribute__((ext_vector_type(16))) float f32x16;

__device__ __forceinline__ unsigned short f2bf_rne(float f) {
    unsigned int u = __float_as_uint(f);
    u += 0x7FFFu + ((u >> 16) & 1u);
    return (unsigned short)(u >> 16);
}

__device__ __forceinline__ void gload16(const void* g, void* l) {
    __builtin_amdgcn_global_load_lds(
        (const __attribute__((address_space(1))) unsigned int*)g,
        (__attribute__((address_space(3))) unsigned int*)l, 16, 0, 0);
}

// ---- kernel 1: convert f32 z_i,z_j -> pre-scaled bf16 fragment-major zf ----
__global__ void convert_kernel(const float* __restrict__ zi,
                               const float* __restrict__ zj,
                               unsigned short* __restrict__ zf) {
    int t = blockIdx.x * 256 + threadIdx.x;   // slot 0..131071
    int l = t & 63;                           // lane slot
    int ks = (t >> 6) & 7;                    // k-step
    int tile = t >> 9;                        // 32-row tile
    int r = tile * 32 + (l & 31);
    int c = (l >> 5) * 8 + ks * 16;
    long si = (long)r * DIM + c;
    const float* src = (si < (long)B_HALF * DIM) ? (zi + si) : (zj + (si - (long)B_HALF * DIM));
    float4 v0 = *(const float4*)src;
    float4 v1 = *(const float4*)(src + 4);
    bf16x8 o;
    o[0] = (short)f2bf_rne(v0.x * PRESCALE);
    o[1] = (short)f2bf_rne(v0.y * PRESCALE);
    o[2] = (short)f2bf_rne(v0.z * PRESCALE);
    o[3] = (short)f2bf_rne(v0.w * PRESCALE);
    o[4] = (short)f2bf_rne(v1.x * PRESCALE);
    o[5] = (short)f2bf_rne(v1.y * PRESCALE);
    o[6] = (short)f2bf_rne(v1.z * PRESCALE);
    o[7] = (short)f2bf_rne(v1.w * PRESCALE);
    *(bf16x8*)(zf + (size_t)t * 8) = o;
}

// consume one 32x32 result tile (acc) for rows [rbase, rbase+32) at
// stream-col base cb into (mv, sv, pv). Deferred-max LSE; wave-uniform skip.
#define CONSUME(accv, mv, sv, pv, rbase, cbv)                                  \
    do {                                                                       \
        const int cb_ = (cbv);                                                 \
        const int rb_ = (rbase);                                               \
        const bool check_ = (cb_ == rb_ || cb_ == (rb_ ^ B_HALF));             \
        if (check_) {                                                          \
            const int j_ = rb_ + l5;                                           \
            _Pragma("unroll")                                                  \
            for (int q = 0; q < 16; ++q) {                                     \
                int iq = cb_ + (q & 3) + 8 * (q >> 2) + 4 * hb;                \
                if (iq == j_) accv[q] = -INFINITY;                             \
                else if (iq == (j_ ^ B_HALF)) pv = accv[q];                    \
            }                                                                  \
        }                                                                      \
        float x0 = fmaxf(fmaxf(accv[0], accv[1]), accv[2]);                    \
        float x1 = fmaxf(fmaxf(accv[3], accv[4]), accv[5]);                    \
        float x2 = fmaxf(fmaxf(accv[6], accv[7]), accv[8]);                    \
        float x3 = fmaxf(fmaxf(accv[9], accv[10]), accv[11]);                  \
        float x4 = fmaxf(fmaxf(accv[12], accv[13]), accv[14]);                 \
        float y0 = fmaxf(fmaxf(x0, x1), x2);                                   \
        float y1 = fmaxf(fmaxf(x3, x4), accv[15]);                             \
        float tmax = fmaxf(y0, y1);                                            \
        if (check_ || !__all(tmax <= mv - SKIP_MARGIN)) {                      \
            float mn = fmaxf(tmax, mv);                                        \
            float rr = __builtin_amdgcn_exp2f(mv - mn); /* exp2(0)=1 */        \
            float e0 = __builtin_amdgcn_exp2f(accv[0] - mn);                   \
            float e1 = __builtin_amdgcn_exp2f(accv[1] - mn);                   \
            float e2 = __builtin_amdgcn_exp2f(accv[2] - mn);                   \
            float e3 = __builtin_amdgcn_exp2f(accv[3] - mn);                   \
            float e4 = __builtin_amdgcn_exp2f(accv[4] - mn);                   \
            float e5 = __builtin_amdgcn_exp2f(accv[5] - mn);                   \
            float e6 = __builtin_amdgcn_exp2f(accv[6] - mn);                   \
            float e7 = __builtin_amdgcn_exp2f(accv[7] - mn);                   \
            float e8 = __builtin_amdgcn_exp2f(accv[8] - mn);                   \
            float e9 = __builtin_amdgcn_exp2f(accv[9] - mn);                   \
            float ea = __builtin_amdgcn_exp2f(accv[10] - mn);                  \
            float eb = __builtin_amdgcn_exp2f(accv[11] - mn);                  \
            float ec = __builtin_amdgcn_exp2f(accv[12] - mn);                  \
            float ed = __builtin_amdgcn_exp2f(accv[13] - mn);                  \
            float ee = __builtin_amdgcn_exp2f(accv[14] - mn);                  \
            float ef = __builtin_amdgcn_exp2f(accv[15] - mn);                  \
            float t0 = (e0 + e1) + (e2 + e3);                                  \
            float t1 = (e4 + e5) + (e6 + e7);                                  \
            float t2 = (e8 + e9) + (ea + eb);                                  \
            float t3 = (ec + ed) + (ee + ef);                                  \
            sv = sv * rr + ((t0 + t1) + (t2 + t3));                            \
            mv = mn;                                                           \
        }                                                                      \
    } while (0)

#define ZERO16(accv)                                                           \
    do { _Pragma("unroll") for (int q = 0; q < 16; ++q) accv[q] = 0.f; } while (0)

// wave w stages fragments 2w, 2w+1 of col-tile (tIdx0 + t) into lds[b]
#define STAGE(t, b)                                                            \
    do {                                                                       \
        const unsigned short* s_ =                                             \
            zf + ((size_t)(tIdx0 + (t)) * 8 + 2 * w) * 512 + l * 8;            \
        gload16(s_, &lds[b][(2 * w) * 64]);                                    \
        gload16(s_ + 512, &lds[b][(2 * w + 1) * 64]);                          \
    } while (0)

#define LDSREAD(Lb)                                                            \
    do {                                                                       \
        f0 = (Lb)[0 * 64 + l];                                                 \
        f1 = (Lb)[1 * 64 + l];                                                 \
        f2 = (Lb)[2 * 64 + l];                                                 \
        f3 = (Lb)[3 * 64 + l];                                                 \
        f4 = (Lb)[4 * 64 + l];                                                 \
        f5 = (Lb)[5 * 64 + l];                                                 \
        f6 = (Lb)[6 * 64 + l];                                                 \
        f7 = (Lb)[7 * 64 + l];                                                 \
    } while (0)

#define MFMA8S(accv)                                                           \
    do {                                                                       \
        accv = __builtin_amdgcn_mfma_f32_32x32x16_bf16(f0, b0, accv, 0, 0, 0); \
        accv = __builtin_amdgcn_mfma_f32_32x32x16_bf16(f1, b1, accv, 0, 0, 0); \
        accv = __builtin_amdgcn_mfma_f32_32x32x16_bf16(f2, b2, accv, 0, 0, 0); \
        accv = __builtin_amdgcn_mfma_f32_32x32x16_bf16(f3, b3, accv, 0, 0, 0); \
        accv = __builtin_amdgcn_mfma_f32_32x32x16_bf16(f4, b4, accv, 0, 0, 0); \
        accv = __builtin_amdgcn_mfma_f32_32x32x16_bf16(f5, b5, accv, 0, 0, 0); \
        accv = __builtin_amdgcn_mfma_f32_32x32x16_bf16(f6, b6, accv, 0, 0, 0); \
        accv = __builtin_amdgcn_mfma_f32_32x32x16_bf16(f7, b7, accv, 0, 0, 0); \
    } while (0)

// pipelined step for tile T (T >= 1): consume tile T-1 while tile T's
// ds_reads are in flight; MFMA(T) issues after; its latency is covered by
// the NEXT step's reads+consume.
#define STEP(T, ACC_C, ACC_P)                                                  \
    do {                                                                       \
        asm volatile("s_waitcnt vmcnt(0)" ::: "memory");                       \
        __builtin_amdgcn_s_barrier();  /* stage(T) landed; buf[(T-1)&1] read-done */ \
        if ((T) + 1 < NT) STAGE((T) + 1, ((T) + 1) & 1);                       \
        __builtin_amdgcn_sched_barrier(0); /* pin stage issue before reads */  \
        LDSREAD(lds[(T) & 1]);                                                 \
        ZERO16(ACC_C);                                                         \
        CONSUME(ACC_P, m0, s0, p0, rowbase, cb0 + ((T) - 1) * 32);             \
        MFMA8S(ACC_C);                                                         \
    } while (0)

// ---- kernel 2: main fused GEMM + online LSE (LDS-staged shared A, reg B) ----
// grid: 64 row-blocks (128 rows: 4 waves x 32) x 32 col-splits (256 cols)
// = 2048 blocks x 256 threads. Wave w owns rows rb*128+w*32; the block's
// 4 waves SHARE each staged 8KB col-tile.
__global__ __launch_bounds__(256, 4) void ntxent_main(
        const unsigned short* __restrict__ zf,
        float* __restrict__ Wm, float* __restrict__ Ws, float* __restrict__ Wp) {
    __shared__ bf16x8 lds[2][512];  // 2 x 8KB col-tile buffers

    const int bid = blockIdx.x;
    const int rb = bid / SPLITS;
    const int sp = bid % SPLITS;
    const int tid = threadIdx.x;
    const int w = tid >> 6;
    const int l = tid & 63;
    const int l5 = l & 31;
    const int hb = l >> 5;

    const int rowbase = rb * 128 + w * 32;
    const int cb0 = sp * COLS_PER_SPLIT;
    const int tIdx0 = cb0 >> 5;

    // B fragments: one 32-row tile-set (8 x 1KB coalesced loads)
    const unsigned short* bp = zf + (size_t)(rowbase >> 5) * 4096 + l * 8;
    bf16x8 b0 = *(const bf16x8*)(bp + 0 * 512);
    bf16x8 b1 = *(const bf16x8*)(bp + 1 * 512);
    bf16x8 b2 = *(const bf16x8*)(bp + 2 * 512);
    bf16x8 b3 = *(const bf16x8*)(bp + 3 * 512);
    bf16x8 b4 = *(const bf16x8*)(bp + 4 * 512);
    bf16x8 b5 = *(const bf16x8*)(bp + 5 * 512);
    bf16x8 b6 = *(const bf16x8*)(bp + 6 * 512);
    bf16x8 b7 = *(const bf16x8*)(bp + 7 * 512);

    float m0 = -INFINITY, s0 = 0.f, p0 = -INFINITY;
    f32x16 accA, accB;
    bf16x8 f0, f1, f2, f3, f4, f5, f6, f7;

    // prologue: stage tile 0+1, compute tile 0 into accA (no consume yet)
    STAGE(0, 0);
    asm volatile("s_waitcnt vmcnt(0)" ::: "memory");
    __builtin_amdgcn_s_barrier();
    STAGE(1, 1);
    __builtin_amdgcn_sched_barrier(0);
    LDSREAD(lds[0]);
    ZERO16(accA);
    MFMA8S(accA);

    // pipelined steps: tile T computed, tile T-1 consumed
    STEP(1, accB, accA);
    STEP(2, accA, accB);
    STEP(3, accB, accA);
    STEP(4, accA, accB);
    STEP(5, accB, accA);
    STEP(6, accA, accB);
    STEP(7, accB, accA);
    // epilogue: consume last tile (7, in accB)
    CONSUME(accB, m0, s0, p0, rowbase, cb0 + 7 * 32);

    // lanes l and l^32 hold the same row over disjoint col subsets: merge
    {
        float m2 = __shfl_xor(m0, 32);
        float s2 = __shfl_xor(s0, 32);
        float q2 = __shfl_xor(p0, 32);
        float M = fmaxf(m0, m2);
        s0 = s0 * __builtin_amdgcn_exp2f(m0 - M) + s2 * __builtin_amdgcn_exp2f(m2 - M);
        p0 = fmaxf(p0, q2);
        if (l < 32) {
            int r = rowbase + l;
            Wm[sp * N_TOT + r] = M;
            Ws[sp * N_TOT + r] = s0;
            Wp[sp * N_TOT + r] = p0;
        }
    }
}

// ---- kernel 3: merge splits, compute loss, reduce ----
__global__ void merge_kernel(const float* __restrict__ Wm,
                             const float* __restrict__ Ws,
                             const float* __restrict__ Wp,
                             float* __restrict__ out) {
    int r = blockIdx.x * 256 + threadIdx.x; // 0..8191
    float m = -INFINITY, s = 0.f, p = -INFINITY;
#pragma unroll
    for (int sb = 0; sb < SPLITS; ++sb) {
        float m2 = Wm[sb * N_TOT + r];
        float s2 = Ws[sb * N_TOT + r];
        float p2 = Wp[sb * N_TOT + r];
        float M = fmaxf(m, m2);
        s = s * __builtin_amdgcn_exp2f(m - M) + s2 * __builtin_amdgcn_exp2f(m2 - M);
        m = M;
        p = fmaxf(p, p2);
    }
    // aug row = [pos, neg-row]: add exp(pos) once more
    s += __builtin_amdgcn_exp2f(p - m);
    float loss = ((m + __builtin_amdgcn_logf(s)) - p) * LN2F;

#pragma unroll
    for (int off = 32; off >= 1; off >>= 1)
        loss += __shfl_down(loss, off);
    __shared__ float wsum[4];
    if ((threadIdx.x & 63) == 0) wsum[threadIdx.x >> 6] = loss;
    __syncthreads();
    if (threadIdx.x == 0) {
        float t = wsum[0] + wsum[1] + wsum[2] + wsum[3];
        atomicAdd(out, t * (1.0f / (float)N_TOT));
    }
}

extern "C" void kernel_launch(void* const* d_in, const int* in_sizes, int n_in,
                              void* d_out, int out_size, void* d_ws, size_t ws_size,
                              hipStream_t stream) {
    const float* zi = (const float*)d_in[0];
    const float* zj = (const float*)d_in[1];
    float* out = (float*)d_out;

    unsigned short* zf = (unsigned short*)d_ws;                // 2 MB
    float* Wm = (float*)((char*)d_ws + (size_t)N_TOT * DIM * 2);
    float* Ws = Wm + SPLITS * N_TOT;
    float* Wp = Ws + SPLITS * N_TOT;

    hipMemsetAsync(d_out, 0, sizeof(float), stream);
    convert_kernel<<<(N_TOT * DIM / 8) / 256, 256, 0, stream>>>(zi, zj, zf);
    ntxent_main<<<64 * SPLITS, 256, 0, stream>>>(zf, Wm, Ws, Wp);
    merge_kernel<<<N_TOT / 256, 256, 0, stream>>>(Wm, Ws, Wp, out);
}

// Round 13
// 43.878 us; speedup vs baseline: 1.0300x; 1.0165x over previous
//
#include <hip/hip_runtime.h>
#include <hip/hip_bf16.h>

// NT-Xent loss, fused flash-LSE over sim = z z^T / T, bf16 32x32x16 MFMA.
// z pre-packed FRAGMENT-MAJOR zf:
//   zf[((tile*8 + ks)*64 + l) * 8 .. +8] =
//       bf16(z[tile*32 + (l&31)][(l>>5)*8 + ks*16 .. +8] * PRESCALE)
// ROUND 13: audit of the dispatch budget. R6 made convert a SCATTER-READ
// kernel (64x32B over 16KB per wave, HBM first-touch, 2 blocks/CU ->
// ~10us latency-bound) and merge runs 32 blocks on 256 CUs (~5-8us).
// Fix overhead, keep R12 main unchanged:
//  - convert: coalesced contiguous reads (thread = 8 consecutive floats),
//    one posted 16B scattered write into zf.
//  - merge: 128 blocks x 64 threads (one row/thread), coalesced loads,
//    single-wave shuffle reduce.

#define N_TOT 8192
#define B_HALF 4096
#define DIM 128
#define SPLITS 32
#define COLS_PER_SPLIT 256
#define NT 8                               // col-tiles of 32 per block
#define PRESCALE 4.5398159686f             // sqrt(log2(e)/0.07)
#define LN2F 0.6931471805599453f
#define SKIP_MARGIN 30.0f                  // skip tile if tmax <= m - 30 (log2)

typedef __attribute__((ext_vector_type(8))) short bf16x8;
typedef __attribute__((ext_vector_type(16))) float f32x16;

__device__ __forceinline__ unsigned short f2bf_rne(float f) {
    unsigned int u = __float_as_uint(f);
    u += 0x7FFFu + ((u >> 16) & 1u);
    return (unsigned short)(u >> 16);
}

__device__ __forceinline__ void gload16(const void* g, void* l) {
    __builtin_amdgcn_global_load_lds(
        (const __attribute__((address_space(1))) unsigned int*)g,
        (__attribute__((address_space(3))) unsigned int*)l, 16, 0, 0);
}

// ---- kernel 1: convert f32 -> pre-scaled bf16 fragment-major zf ----
// COALESCED READS: thread g handles 8 consecutive floats (row r = g/16,
// c0 = (g%16)*8); wave reads contiguous 2KB. One scattered 16B write.
__global__ void convert_kernel(const float* __restrict__ zi,
                               const float* __restrict__ zj,
                               unsigned short* __restrict__ zf) {
    int g = blockIdx.x * 256 + threadIdx.x;   // 0..131071
    long si = (long)g * 8;
    const float* src = (si < (long)B_HALF * DIM) ? (zi + si) : (zj + (si - (long)B_HALF * DIM));
    float4 v0 = *(const float4*)src;
    float4 v1 = *(const float4*)(src + 4);
    bf16x8 o;
    o[0] = (short)f2bf_rne(v0.x * PRESCALE);
    o[1] = (short)f2bf_rne(v0.y * PRESCALE);
    o[2] = (short)f2bf_rne(v0.z * PRESCALE);
    o[3] = (short)f2bf_rne(v0.w * PRESCALE);
    o[4] = (short)f2bf_rne(v1.x * PRESCALE);
    o[5] = (short)f2bf_rne(v1.y * PRESCALE);
    o[6] = (short)f2bf_rne(v1.z * PRESCALE);
    o[7] = (short)f2bf_rne(v1.w * PRESCALE);
    int r = g >> 4;                 // row 0..8191
    int ks = (g & 15) >> 1;         // k-step 0..7
    int hb = g & 1;                 // k-half
    long slot = ((long)(r >> 5) * 8 + ks) * 64 + hb * 32 + (r & 31);
    *(bf16x8*)(zf + slot * 8) = o;
}

// consume one 32x32 result tile (acc) for rows [rbase, rbase+32) at
// stream-col base cb into (mv, sv, pv). Deferred-max LSE; wave-uniform skip.
#define CONSUME(accv, mv, sv, pv, rbase, cbv)                                  \
    do {                                                                       \
        const int cb_ = (cbv);                                                 \
        const int rb_ = (rbase);                                               \
        const bool check_ = (cb_ == rb_ || cb_ == (rb_ ^ B_HALF));             \
        if (check_) {                                                          \
            const int j_ = rb_ + l5;                                           \
            _Pragma("unroll")                                                  \
            for (int q = 0; q < 16; ++q) {                                     \
                int iq = cb_ + (q & 3) + 8 * (q >> 2) + 4 * hb;                \
                if (iq == j_) accv[q] = -INFINITY;                             \
                else if (iq == (j_ ^ B_HALF)) pv = accv[q];                    \
            }                                                                  \
        }                                                                      \
        float x0 = fmaxf(fmaxf(accv[0], accv[1]), accv[2]);                    \
        float x1 = fmaxf(fmaxf(accv[3], accv[4]), accv[5]);                    \
        float x2 = fmaxf(fmaxf(accv[6], accv[7]), accv[8]);                    \
        float x3 = fmaxf(fmaxf(accv[9], accv[10]), accv[11]);                  \
        float x4 = fmaxf(fmaxf(accv[12], accv[13]), accv[14]);                 \
        float y0 = fmaxf(fmaxf(x0, x1), x2);                                   \
        float y1 = fmaxf(fmaxf(x3, x4), accv[15]);                             \
        float tmax = fmaxf(y0, y1);                                            \
        if (check_ || !__all(tmax <= mv - SKIP_MARGIN)) {                      \
            float mn = fmaxf(tmax, mv);                                        \
            float rr = __builtin_amdgcn_exp2f(mv - mn); /* exp2(0)=1 */        \
            float e0 = __builtin_amdgcn_exp2f(accv[0] - mn);                   \
            float e1 = __builtin_amdgcn_exp2f(accv[1] - mn);                   \
            float e2 = __builtin_amdgcn_exp2f(accv[2] - mn);                   \
            float e3 = __builtin_amdgcn_exp2f(accv[3] - mn);                   \
            float e4 = __builtin_amdgcn_exp2f(accv[4] - mn);                   \
            float e5 = __builtin_amdgcn_exp2f(accv[5] - mn);                   \
            float e6 = __builtin_amdgcn_exp2f(accv[6] - mn);                   \
            float e7 = __builtin_amdgcn_exp2f(accv[7] - mn);                   \
            float e8 = __builtin_amdgcn_exp2f(accv[8] - mn);                   \
            float e9 = __builtin_amdgcn_exp2f(accv[9] - mn);                   \
            float ea = __builtin_amdgcn_exp2f(accv[10] - mn);                  \
            float eb = __builtin_amdgcn_exp2f(accv[11] - mn);                  \
            float ec = __builtin_amdgcn_exp2f(accv[12] - mn);                  \
            float ed = __builtin_amdgcn_exp2f(accv[13] - mn);                  \
            float ee = __builtin_amdgcn_exp2f(accv[14] - mn);                  \
            float ef = __builtin_amdgcn_exp2f(accv[15] - mn);                  \
            float t0 = (e0 + e1) + (e2 + e3);                                  \
            float t1 = (e4 + e5) + (e6 + e7);                                  \
            float t2 = (e8 + e9) + (ea + eb);                                  \
            float t3 = (ec + ed) + (ee + ef);                                  \
            sv = sv * rr + ((t0 + t1) + (t2 + t3));                            \
            mv = mn;                                                           \
        }                                                                      \
    } while (0)

#define ZERO16(accv)                                                           \
    do { _Pragma("unroll") for (int q = 0; q < 16; ++q) accv[q] = 0.f; } while (0)

// wave w stages fragments 2w, 2w+1 of col-tile (tIdx0 + t) into lds[b]
#define STAGE(t, b)                                                            \
    do {                                                                       \
        const unsigned short* s_ =                                             \
            zf + ((size_t)(tIdx0 + (t)) * 8 + 2 * w) * 512 + l * 8;            \
        gload16(s_, &lds[b][(2 * w) * 64]);                                    \
        gload16(s_ + 512, &lds[b][(2 * w + 1) * 64]);                          \
    } while (0)

#define LDSREAD(Lb)                                                            \
    do {                                                                       \
        f0 = (Lb)[0 * 64 + l];                                                 \
        f1 = (Lb)[1 * 64 + l];                                                 \
        f2 = (Lb)[2 * 64 + l];                                                 \
        f3 = (Lb)[3 * 64 + l];                                                 \
        f4 = (Lb)[4 * 64 + l];                                                 \
        f5 = (Lb)[5 * 64 + l];                                                 \
        f6 = (Lb)[6 * 64 + l];                                                 \
        f7 = (Lb)[7 * 64 + l];                                                 \
    } while (0)

#define MFMA8S(accv)                                                           \
    do {                                                                       \
        accv = __builtin_amdgcn_mfma_f32_32x32x16_bf16(f0, b0, accv, 0, 0, 0); \
        accv = __builtin_amdgcn_mfma_f32_32x32x16_bf16(f1, b1, accv, 0, 0, 0); \
        accv = __builtin_amdgcn_mfma_f32_32x32x16_bf16(f2, b2, accv, 0, 0, 0); \
        accv = __builtin_amdgcn_mfma_f32_32x32x16_bf16(f3, b3, accv, 0, 0, 0); \
        accv = __builtin_amdgcn_mfma_f32_32x32x16_bf16(f4, b4, accv, 0, 0, 0); \
        accv = __builtin_amdgcn_mfma_f32_32x32x16_bf16(f5, b5, accv, 0, 0, 0); \
        accv = __builtin_amdgcn_mfma_f32_32x32x16_bf16(f6, b6, accv, 0, 0, 0); \
        accv = __builtin_amdgcn_mfma_f32_32x32x16_bf16(f7, b7, accv, 0, 0, 0); \
    } while (0)

// pipelined step for tile T (T >= 1): consume tile T-1 while tile T's
// ds_reads are in flight; MFMA(T) issues after.
#define STEP(T, ACC_C, ACC_P)                                                  \
    do {                                                                       \
        asm volatile("s_waitcnt vmcnt(0)" ::: "memory");                       \
        __builtin_amdgcn_s_barrier();                                          \
        if ((T) + 1 < NT) STAGE((T) + 1, ((T) + 1) & 1);                       \
        __builtin_amdgcn_sched_barrier(0);                                     \
        LDSREAD(lds[(T) & 1]);                                                 \
        ZERO16(ACC_C);                                                         \
        CONSUME(ACC_P, m0, s0, p0, rowbase, cb0 + ((T) - 1) * 32);             \
        MFMA8S(ACC_C);                                                         \
    } while (0)

// ---- kernel 2: main fused GEMM + online LSE (LDS-staged shared A, reg B) ----
// grid: 64 row-blocks (128 rows: 4 waves x 32) x 32 col-splits (256 cols)
// = 2048 blocks x 256 threads.
__global__ __launch_bounds__(256, 4) void ntxent_main(
        const unsigned short* __restrict__ zf,
        float* __restrict__ Wm, float* __restrict__ Ws, float* __restrict__ Wp) {
    __shared__ bf16x8 lds[2][512];  // 2 x 8KB col-tile buffers

    const int bid = blockIdx.x;
    const int rb = bid / SPLITS;
    const int sp = bid % SPLITS;
    const int tid = threadIdx.x;
    const int w = tid >> 6;
    const int l = tid & 63;
    const int l5 = l & 31;
    const int hb = l >> 5;

    const int rowbase = rb * 128 + w * 32;
    const int cb0 = sp * COLS_PER_SPLIT;
    const int tIdx0 = cb0 >> 5;

    // B fragments: one 32-row tile-set (8 x 1KB coalesced loads)
    const unsigned short* bp = zf + (size_t)(rowbase >> 5) * 4096 + l * 8;
    bf16x8 b0 = *(const bf16x8*)(bp + 0 * 512);
    bf16x8 b1 = *(const bf16x8*)(bp + 1 * 512);
    bf16x8 b2 = *(const bf16x8*)(bp + 2 * 512);
    bf16x8 b3 = *(const bf16x8*)(bp + 3 * 512);
    bf16x8 b4 = *(const bf16x8*)(bp + 4 * 512);
    bf16x8 b5 = *(const bf16x8*)(bp + 5 * 512);
    bf16x8 b6 = *(const bf16x8*)(bp + 6 * 512);
    bf16x8 b7 = *(const bf16x8*)(bp + 7 * 512);

    float m0 = -INFINITY, s0 = 0.f, p0 = -INFINITY;
    f32x16 accA, accB;
    bf16x8 f0, f1, f2, f3, f4, f5, f6, f7;

    // prologue: stage tile 0+1, compute tile 0 into accA (no consume yet)
    STAGE(0, 0);
    asm volatile("s_waitcnt vmcnt(0)" ::: "memory");
    __builtin_amdgcn_s_barrier();
    STAGE(1, 1);
    __builtin_amdgcn_sched_barrier(0);
    LDSREAD(lds[0]);
    ZERO16(accA);
    MFMA8S(accA);

    STEP(1, accB, accA);
    STEP(2, accA, accB);
    STEP(3, accB, accA);
    STEP(4, accA, accB);
    STEP(5, accB, accA);
    STEP(6, accA, accB);
    STEP(7, accB, accA);
    CONSUME(accB, m0, s0, p0, rowbase, cb0 + 7 * 32);

    // lanes l and l^32 hold the same row over disjoint col subsets: merge
    {
        float m2 = __shfl_xor(m0, 32);
        float s2 = __shfl_xor(s0, 32);
        float q2 = __shfl_xor(p0, 32);
        float M = fmaxf(m0, m2);
        s0 = s0 * __builtin_amdgcn_exp2f(m0 - M) + s2 * __builtin_amdgcn_exp2f(m2 - M);
        p0 = fmaxf(p0, q2);
        if (l < 32) {
            int r = rowbase + l;
            Wm[sp * N_TOT + r] = M;
            Ws[sp * N_TOT + r] = s0;
            Wp[sp * N_TOT + r] = p0;
        }
    }
}

// ---- kernel 3: merge splits, compute loss, reduce ----
// 128 blocks x 64 threads (one wave): one row per thread, coalesced reads.
__global__ __launch_bounds__(64) void merge_kernel(
        const float* __restrict__ Wm, const float* __restrict__ Ws,
        const float* __restrict__ Wp, float* __restrict__ out) {
    int r = blockIdx.x * 64 + threadIdx.x; // 0..8191
    float m = -INFINITY, s = 0.f, p = -INFINITY;
#pragma unroll
    for (int sb = 0; sb < SPLITS; ++sb) {
        float m2 = Wm[sb * N_TOT + r];
        float s2 = Ws[sb * N_TOT + r];
        float p2 = Wp[sb * N_TOT + r];
        float M = fmaxf(m, m2);
        s = s * __builtin_amdgcn_exp2f(m - M) + s2 * __builtin_amdgcn_exp2f(m2 - M);
        m = M;
        p = fmaxf(p, p2);
    }
    // aug row = [pos, neg-row]: add exp(pos) once more
    s += __builtin_amdgcn_exp2f(p - m);
    float loss = ((m + __builtin_amdgcn_logf(s)) - p) * LN2F;

#pragma unroll
    for (int off = 32; off >= 1; off >>= 1)
        loss += __shfl_down(loss, off);
    if (threadIdx.x == 0)
        atomicAdd(out, loss * (1.0f / (float)N_TOT));
}

extern "C" void kernel_launch(void* const* d_in, const int* in_sizes, int n_in,
                              void* d_out, int out_size, void* d_ws, size_t ws_size,
                              hipStream_t stream) {
    const float* zi = (const float*)d_in[0];
    const float* zj = (const float*)d_in[1];
    float* out = (float*)d_out;

    unsigned short* zf = (unsigned short*)d_ws;                // 2 MB
    float* Wm = (float*)((char*)d_ws + (size_t)N_TOT * DIM * 2);
    float* Ws = Wm + SPLITS * N_TOT;
    float* Wp = Ws + SPLITS * N_TOT;

    hipMemsetAsync(d_out, 0, sizeof(float), stream);
    convert_kernel<<<512, 256, 0, stream>>>(zi, zj, zf);
    ntxent_main<<<64 * SPLITS, 256, 0, stream>>>(zf, Wm, Ws, Wp);
    merge_kernel<<<128, 64, 0, stream>>>(Wm, Ws, Wp, out);
}